// Round 5
// baseline (163.265 us; speedup 1.0000x reference)
//
#include <hip/hip_runtime.h>
#include <stdint.h>

typedef unsigned long long u64;

#define IN_C 256
#define HID_C 128
#define SRC_CAP 192   // per-node neighbor-list cap (deg ~Poisson(32); P(>192)~1e-80)
#define MM_CAP 256
#define CHUNK 32
#define PAD 132       // LDS row pad: 132*4=528 B keeps 16B alignment per row

// 40 MB fallback scratch in case d_ws is too small (BSS, module-owned).
__device__ __align__(256) unsigned char g_fallback[40u << 20];

// ---------------- shared GEMM body: C[16 rows][128] = relu(X@W^T + b), optional row norms ----------------
__device__ inline void gemm_body(int bid, int tid,
                                 const float* __restrict__ X, const float* __restrict__ W,
                                 const float* __restrict__ b, float* __restrict__ C, int K,
                                 float* __restrict__ ssq_out, float* __restrict__ invn_out,
                                 float (*Ws)[HID_C + 4], float (*Xs)[64]) {
  const int rl = tid >> 5;       // 0..7  (row pair)
  const int cg = tid & 31;       // 0..31 (col group of 4)
  const int row0 = bid * 16;
  float4 acc0 = make_float4(0.f, 0.f, 0.f, 0.f);
  float4 acc1 = make_float4(0.f, 0.f, 0.f, 0.f);
  for (int kt = 0; kt < K; kt += 64) {
    for (int idx = tid; idx < HID_C * 16; idx += 256) {
      int c = idx >> 4, kq = idx & 15;
      const float4 w4 = *(const float4*)&W[c * K + kt + kq * 4];
      Ws[kq * 4 + 0][c] = w4.x;
      Ws[kq * 4 + 1][c] = w4.y;
      Ws[kq * 4 + 2][c] = w4.z;
      Ws[kq * 4 + 3][c] = w4.w;
    }
    {
      int r = tid >> 4, kq = tid & 15;
      const float4 x4 = *(const float4*)&X[(row0 + r) * K + kt + kq * 4];
      *(float4*)&Xs[r][kq * 4] = x4;
    }
    __syncthreads();
#pragma unroll 16
    for (int kk = 0; kk < 64; ++kk) {
      const float4 w = *(const float4*)&Ws[kk][cg * 4];
      const float x0 = Xs[rl * 2 + 0][kk];
      const float x1 = Xs[rl * 2 + 1][kk];
      acc0.x = fmaf(w.x, x0, acc0.x); acc0.y = fmaf(w.y, x0, acc0.y);
      acc0.z = fmaf(w.z, x0, acc0.z); acc0.w = fmaf(w.w, x0, acc0.w);
      acc1.x = fmaf(w.x, x1, acc1.x); acc1.y = fmaf(w.y, x1, acc1.y);
      acc1.z = fmaf(w.z, x1, acc1.z); acc1.w = fmaf(w.w, x1, acc1.w);
    }
    __syncthreads();
  }
  const float4 bb = *(const float4*)&b[cg * 4];
  float4 o0, o1;
  o0.x = fmaxf(acc0.x + bb.x, 0.f); o0.y = fmaxf(acc0.y + bb.y, 0.f);
  o0.z = fmaxf(acc0.z + bb.z, 0.f); o0.w = fmaxf(acc0.w + bb.w, 0.f);
  o1.x = fmaxf(acc1.x + bb.x, 0.f); o1.y = fmaxf(acc1.y + bb.y, 0.f);
  o1.z = fmaxf(acc1.z + bb.z, 0.f); o1.w = fmaxf(acc1.w + bb.w, 0.f);
  int r0 = row0 + rl * 2;
  *(float4*)&C[r0 * HID_C + cg * 4] = o0;
  *(float4*)&C[(r0 + 1) * HID_C + cg * 4] = o1;
  if (ssq_out) {
    float s0 = o0.x * o0.x + o0.y * o0.y + o0.z * o0.z + o0.w * o0.w;
    float s1 = o1.x * o1.x + o1.y * o1.y + o1.z * o1.z + o1.w * o1.w;
#pragma unroll
    for (int off = 16; off >= 1; off >>= 1) {
      s0 += __shfl_xor(s0, off, 64);
      s1 += __shfl_xor(s1, off, 64);
    }
    if (cg == 0) {
      ssq_out[r0] = s0;
      ssq_out[r0 + 1] = s1;
      invn_out[r0] = 1.0f / fmaxf(sqrtf(s0), 1e-12f);
      invn_out[r0 + 1] = 1.0f / fmaxf(sqrtf(s1), 1e-12f);
    }
  }
}

// ---------------- fused: blocks [0,nblk_gemm) do GEMM1; the rest build bitmaps + dup list ----------------
__global__ __launch_bounds__(256) void k_build_gemm(
    const float* __restrict__ X, const float* __restrict__ W, const float* __restrict__ b,
    float* __restrict__ C, int K, float* __restrict__ ssq_out, float* __restrict__ invn_out,
    int nblk_gemm,
    const int* __restrict__ src, const int* __restrict__ dst, int E,
    u64* __restrict__ bmT, u64* __restrict__ bmS, int wpr,
    u64* __restrict__ duplist, int* __restrict__ dupcnt, int dupcap) {
  __shared__ float Ws[64][HID_C + 4];
  __shared__ float Xs[16][64];
  if ((int)blockIdx.x < nblk_gemm) {
    gemm_body(blockIdx.x, threadIdx.x, X, W, b, C, K, ssq_out, invn_out, Ws, Xs);
    return;
  }
  int e = (blockIdx.x - nblk_gemm) * 256 + threadIdx.x;
  if (e < E) {
    int s = src[e], d = dst[e];
    u64 bit = 1ull << (s & 63);
    u64 old = atomicOr(&bmT[(size_t)d * wpr + (s >> 6)], bit);
    if (old & bit) {  // duplicate edge (multiplicity-1 extra copies recorded)
      int i = atomicAdd(dupcnt, 1);
      if (i < dupcap) duplist[i] = ((u64)(uint32_t)d << 32) | (uint32_t)s;
    }
    atomicOr(&bmS[(size_t)s * wpr + (d >> 6)], 1ull << (d & 63));
  }
}

// ---------------- standalone GEMM (second layer) ----------------
__global__ __launch_bounds__(256) void k_gemm_relu(
    const float* __restrict__ X, const float* __restrict__ W,
    const float* __restrict__ b, float* __restrict__ C, int K,
    float* __restrict__ ssq_out, float* __restrict__ invn_out) {
  __shared__ float Ws[64][HID_C + 4];
  __shared__ float Xs[16][64];
  gemm_body(blockIdx.x, threadIdx.x, X, W, b, C, K, ssq_out, invn_out, Ws, Xs);
}

// ---------------- AGNN propagation: one wave per dst node, LDS-tile dots (no per-edge shfl) ----------------
__global__ __launch_bounds__(64) void k_agg(
    const float* __restrict__ hin, float* __restrict__ hout,
    const u64* __restrict__ bmT, int wpr,
    const u64* __restrict__ duplist, const int* __restrict__ dupcnt, int dupcap,
    int* __restrict__ glist, int* __restrict__ gdeg, int enumerate,
    const float* __restrict__ invn, const float* __restrict__ ssq,
    const float* __restrict__ beta_ptr,
    float* __restrict__ ssq_out, float* __restrict__ invn_out, int n) {
  __shared__ int   s_src[SRC_CAP];
  __shared__ float s_inv[SRC_CAP];
  __shared__ float s_w[CHUNK];
  __shared__ float s_h[CHUNK][PAD];
  __shared__ float s_hd[HID_C];
  int wid = blockIdx.x;
  int lane = threadIdx.x;
  int M;

  if (enumerate) {
    // ---- enumerate src list from transpose-bitmap (fixed deterministic order) ----
    const u64* row = bmT + (size_t)wid * wpr;
    u64 w0 = row[lane];
    u64 w1 = row[64 + lane];
    int c = __popcll(w0) + __popcll(w1);
    int incl = c;
#pragma unroll
    for (int off = 1; off < 64; off <<= 1) {
      int v = __shfl_up(incl, off, 64);
      if (lane >= off) incl += v;
    }
    M = __shfl(incl, 63, 64);
    int pos = incl - c;
    u64 t = w0;
    while (t) {
      int bpos = __ffsll(t) - 1; t &= t - 1;
      if (pos < SRC_CAP) s_src[pos] = (lane << 6) + bpos;
      pos++;
    }
    t = w1;
    while (t) {
      int bpos = __ffsll(t) - 1; t &= t - 1;
      if (pos < SRC_CAP) s_src[pos] = ((64 + lane) << 6) + bpos;
      pos++;
    }
    if (M > SRC_CAP) M = SRC_CAP;
    // ---- append duplicate edges (ascending s, multiplicity-exact, deterministic) ----
    int D = min(*dupcnt, dupcap);
    for (int base = 0; base < D; base += 64) {
      int m = min(64, D - base);
      bool match = false; int sE = 0x7fffffff;
      if (lane < m) {
        u64 ent = duplist[base + lane];
        if ((int)(ent >> 32) == wid) { match = true; sE = (int)(uint32_t)ent; }
      }
      while (__ballot(match)) {
        int sv = match ? sE : 0x7fffffff;
#pragma unroll
        for (int o = 32; o >= 1; o >>= 1) sv = min(sv, __shfl_xor(sv, o, 64));
        int cnt = (int)__popcll(__ballot(match && sE == sv));
        if (lane < cnt && M + lane < SRC_CAP) s_src[M + lane] = sv;
        M = min(M + cnt, SRC_CAP);
        if (match && sE == sv) match = false;
      }
    }
    __syncthreads();
    // persist for prop2
    for (int i = lane; i < M; i += 64) glist[wid * SRC_CAP + i] = s_src[i];
    if (lane == 0) gdeg[wid] = M;
  } else {
    M = gdeg[wid];
    for (int i = lane; i < M; i += 64) s_src[i] = glist[wid * SRC_CAP + i];
    __syncthreads();
  }

  // per-src inv-norms + dst row into LDS
  for (int i = lane; i < M; i += 64) s_inv[i] = invn[s_src[i]];
  float2 hd = *(const float2*)&hin[wid * HID_C + lane * 2];
  *(float2*)&s_hd[lane * 2] = hd;

  float beta = beta_ptr ? beta_ptr[0] : 1.0f;
  float invd = invn[wid];
  float eloop = __expf(beta * (ssq[wid] * invd) * invd);  // self-loop; 0-row safe
  float ssum = eloop;
  float2 acc = make_float2(eloop * hd.x, eloop * hd.y);

  const int e = lane >> 1, hf = lane & 1;
  for (int cb = 0; cb < M; cb += CHUNK) {
    int m = min(CHUNK, M - cb);
    // stage m neighbor rows into LDS (coalesced float4)
    for (int idx = lane; idx < m * 32; idx += 64) {
      int r = idx >> 5, q = idx & 31;
      int s = s_src[cb + r];
      float4 v = *(const float4*)&hin[s * HID_C + q * 4];
      *(float4*)&s_h[r][q * 4] = v;
    }
    __syncthreads();
    // per-lane-pair dot over 64 features each
    float d = 0.f;
    if (e < m) {
      const float* hr = &s_h[e][hf * 64];
      const float* hq = &s_hd[hf * 64];
#pragma unroll 16
      for (int j = 0; j < 64; j += 4) {
        float4 a = *(const float4*)&hr[j];
        float4 q4 = *(const float4*)&hq[j];
        d = fmaf(a.x, q4.x, d); d = fmaf(a.y, q4.y, d);
        d = fmaf(a.z, q4.z, d); d = fmaf(a.w, q4.w, d);
      }
    }
    d += __shfl_xor(d, 1, 64);  // one cross-lane op per chunk-lane
    if (e < m && hf == 0) {
      s_w[e] = __expf(beta * d * invd * s_inv[cb + e]);
    }
    __syncthreads();
    // aggregate from LDS tile (broadcast weights, no cross-lane)
    for (int t2 = 0; t2 < m; ++t2) {
      float w = s_w[t2];
      ssum += w;
      acc.x = fmaf(w, s_h[t2][lane * 2 + 0], acc.x);
      acc.y = fmaf(w, s_h[t2][lane * 2 + 1], acc.y);
    }
    __syncthreads();
  }

  float winv = 1.0f / (ssum + 1e-16f);
  acc.x *= winv; acc.y *= winv;
  *(float2*)&hout[wid * HID_C + lane * 2] = acc;
  if (ssq_out) {
    float s = acc.x * acc.x + acc.y * acc.y;
#pragma unroll
    for (int off = 32; off >= 1; off >>= 1) s += __shfl_xor(s, off, 64);
    if (lane == 0) {
      ssq_out[wid] = s;
      invn_out[wid] = 1.0f / fmaxf(sqrtf(s), 1e-12f);
    }
  }
}

// ---------------- out = adj @ h: enumerate row bits once, then clean gather-add loop ----------------
__global__ __launch_bounds__(64) void k_mm_bits(
    const u64* __restrict__ bm, const float* __restrict__ h,
    float* __restrict__ out, int n, int wpr) {
  __shared__ int s_idx[MM_CAP];
  int wid = blockIdx.x;
  int lane = threadIdx.x;
  const u64* row = bm + (size_t)wid * wpr;
  u64 w0 = row[lane];
  u64 w1 = row[64 + lane];
  int c = __popcll(w0) + __popcll(w1);
  int incl = c;
#pragma unroll
  for (int off = 1; off < 64; off <<= 1) {
    int v = __shfl_up(incl, off, 64);
    if (lane >= off) incl += v;
  }
  int M = __shfl(incl, 63, 64);
  int pos = incl - c;
  u64 t = w0;
  while (t) {
    int bpos = __ffsll(t) - 1; t &= t - 1;
    if (pos < MM_CAP) s_idx[pos] = (lane << 6) + bpos;
    pos++;
  }
  t = w1;
  while (t) {
    int bpos = __ffsll(t) - 1; t &= t - 1;
    if (pos < MM_CAP) s_idx[pos] = ((64 + lane) << 6) + bpos;
    pos++;
  }
  if (M > MM_CAP) M = MM_CAP;
  __syncthreads();
  float2 acc = make_float2(0.f, 0.f);
  for (int i = 0; i < M; ++i) {
    int k = s_idx[i];  // LDS broadcast
    float2 hv = *(const float2*)&h[k * HID_C + lane * 2];
    acc.x += hv.x;
    acc.y += hv.y;
  }
  *(float2*)&out[wid * HID_C + lane * 2] = acc;
}

extern "C" void kernel_launch(void* const* d_in, const int* in_sizes, int n_in,
                              void* d_out, int out_size, void* d_ws, size_t ws_size,
                              hipStream_t stream) {
  const float* x     = (const float*)d_in[0];
  const int*   eio   = (const int*)d_in[2];
  const float* W1    = (const float*)d_in[3];
  const float* b1    = (const float*)d_in[4];
  const float* W2    = (const float*)d_in[5];
  const float* b2    = (const float*)d_in[6];
  const float* beta2 = (const float*)d_in[7];
  float* out = (float*)d_out;

  const int N = in_sizes[0] / IN_C;   // 8192
  const int E = in_sizes[2] / 2;      // 262144
  const int WPR = N / 64;             // bitmap words per row (128)
  const int* esrc = eio;
  const int* edst = eio + E;
  const int DUPCAP = E;

  // ---- workspace layout (256B aligned slots) ----
  size_t off = 0;
  auto take = [&](size_t bytes) -> size_t {
    size_t o = off;
    off = (off + bytes + 255) & ~(size_t)255;
    return o;
  };
  size_t o_bufA   = take((size_t)N * HID_C * 4);
  size_t o_bufB   = take((size_t)N * HID_C * 4);
  size_t o_invnA  = take((size_t)N * 4);
  size_t o_ssqA   = take((size_t)N * 4);
  size_t o_invnB  = take((size_t)N * 4);
  size_t o_ssqB   = take((size_t)N * 4);
  size_t o_glist  = take((size_t)N * SRC_CAP * 4);
  size_t o_gdeg   = take((size_t)N * 4);
  size_t o_bmT    = take((size_t)N * WPR * 8);   // zeroed region starts here
  size_t o_bmS    = take((size_t)N * WPR * 8);
  size_t o_dupcnt = take(256);
  size_t need_zero_end = o_dupcnt + 256;
  size_t o_duplist = take((size_t)DUPCAP * 8);
  size_t need_full = off;

  unsigned char* base = (unsigned char*)d_ws;
  if (ws_size < need_full) {
    void* p = nullptr;
    hipGetSymbolAddress(&p, HIP_SYMBOL(g_fallback));
    base = (unsigned char*)p;
  }

  float* bufA    = (float*)(base + o_bufA);
  float* bufB    = (float*)(base + o_bufB);
  float* invnA   = (float*)(base + o_invnA);
  float* ssqA    = (float*)(base + o_ssqA);
  float* invnB   = (float*)(base + o_invnB);
  float* ssqB    = (float*)(base + o_ssqB);
  int*   glist   = (int*)(base + o_glist);
  int*   gdeg    = (int*)(base + o_gdeg);
  u64*   bmT     = (u64*)(base + o_bmT);
  u64*   bmS     = (u64*)(base + o_bmS);
  int*   dupcnt  = (int*)(base + o_dupcnt);
  u64*   duplist = (u64*)(base + o_duplist);

  dim3 blk(256);

  // 1. zero bitmaps + dup counter (one contiguous async memset — graph-capturable)
  hipMemsetAsync(base + o_bmT, 0, need_zero_end - o_bmT, stream);

  // 2. fused: GEMM1 (h1 = relu(x@W1^T+b1) + norms) || bitmap/dup build
  {
    int nblk_gemm = N / 16;                  // 512
    int nblk_build = (E + 255) / 256;        // 1024
    k_build_gemm<<<dim3(nblk_gemm + nblk_build), blk, 0, stream>>>(
        x, W1, b1, bufA, IN_C, ssqA, invnA, nblk_gemm,
        esrc, edst, E, bmT, bmS, WPR, duplist, dupcnt, DUPCAP);
  }

  // 3. prop1 (beta = 1.0): enumerate + persist list, + output row norms
  k_agg<<<dim3(N), dim3(64), 0, stream>>>(bufA, bufB, bmT, WPR, duplist, dupcnt, DUPCAP,
                                          glist, gdeg, 1,
                                          invnA, ssqA, nullptr, ssqB, invnB, N);

  // 4. prop2 (beta = beta2[0]): reuse list
  k_agg<<<dim3(N), dim3(64), 0, stream>>>(bufB, bufA, bmT, WPR, duplist, dupcnt, DUPCAP,
                                          glist, gdeg, 0,
                                          invnB, ssqB, beta2, nullptr, nullptr, N);

  // 5. h3 = relu(h @ W2^T + b2)
  k_gemm_relu<<<dim3(N / 16), blk, 0, stream>>>(bufA, W2, b2, bufB, HID_C, nullptr, nullptr);

  // 6. out = adj @ h3
  k_mm_bits<<<dim3(N), dim3(64), 0, stream>>>(bmS, bufB, out, N, WPR);
}

// Round 6
// 151.759 us; speedup vs baseline: 1.0758x; 1.0758x over previous
//
#include <hip/hip_runtime.h>
#include <stdint.h>

typedef unsigned long long u64;

#define IN_C 256
#define HID_C 128
#define SRC_CAP 192   // per-wave LDS src-list capacity (deg ~Poisson(32); P(>192)≈0)

// 28 MB fallback scratch in case d_ws is too small (BSS, module-owned).
__device__ __align__(256) unsigned char g_fallback[28u << 20];

__device__ inline u64 shfl_u64(u64 v, int srclane) {
  int lo = __shfl((int)(v & 0xffffffffull), srclane, 64);
  int hi = __shfl((int)(v >> 32), srclane, 64);
  return ((u64)(uint32_t)hi << 32) | (uint32_t)lo;
}

// ---------------- fast zero (the rocclr fill kernel runs tiny fills at ~100 GB/s) ----------------
__global__ void k_zero128(uint4* __restrict__ p, int n16) {
  int i = blockIdx.x * blockDim.x + threadIdx.x;
  int stride = gridDim.x * blockDim.x;
  uint4 z = make_uint4(0u, 0u, 0u, 0u);
  for (; i < n16; i += stride) p[i] = z;
}

// ---------------- shared GEMM body: C[16 rows][128] = relu(X@W^T + b), optional row norms ----------------
__device__ inline void gemm_body(int bid, int tid,
                                 const float* __restrict__ X, const float* __restrict__ W,
                                 const float* __restrict__ b, float* __restrict__ C, int K,
                                 float* __restrict__ ssq_out, float* __restrict__ invn_out,
                                 float (*Ws)[HID_C + 4], float (*Xs)[64]) {
  const int rl = tid >> 5;       // 0..7  (row pair)
  const int cg = tid & 31;       // 0..31 (col group of 4)
  const int row0 = bid * 16;
  float4 acc0 = make_float4(0.f, 0.f, 0.f, 0.f);
  float4 acc1 = make_float4(0.f, 0.f, 0.f, 0.f);
  for (int kt = 0; kt < K; kt += 64) {
    for (int idx = tid; idx < HID_C * 16; idx += 256) {
      int c = idx >> 4, kq = idx & 15;
      const float4 w4 = *(const float4*)&W[c * K + kt + kq * 4];
      Ws[kq * 4 + 0][c] = w4.x;
      Ws[kq * 4 + 1][c] = w4.y;
      Ws[kq * 4 + 2][c] = w4.z;
      Ws[kq * 4 + 3][c] = w4.w;
    }
    {
      int r = tid >> 4, kq = tid & 15;
      const float4 x4 = *(const float4*)&X[(row0 + r) * K + kt + kq * 4];
      *(float4*)&Xs[r][kq * 4] = x4;
    }
    __syncthreads();
#pragma unroll 16
    for (int kk = 0; kk < 64; ++kk) {
      const float4 w = *(const float4*)&Ws[kk][cg * 4];
      const float x0 = Xs[rl * 2 + 0][kk];
      const float x1 = Xs[rl * 2 + 1][kk];
      acc0.x = fmaf(w.x, x0, acc0.x); acc0.y = fmaf(w.y, x0, acc0.y);
      acc0.z = fmaf(w.z, x0, acc0.z); acc0.w = fmaf(w.w, x0, acc0.w);
      acc1.x = fmaf(w.x, x1, acc1.x); acc1.y = fmaf(w.y, x1, acc1.y);
      acc1.z = fmaf(w.z, x1, acc1.z); acc1.w = fmaf(w.w, x1, acc1.w);
    }
    __syncthreads();
  }
  const float4 bb = *(const float4*)&b[cg * 4];
  float4 o0, o1;
  o0.x = fmaxf(acc0.x + bb.x, 0.f); o0.y = fmaxf(acc0.y + bb.y, 0.f);
  o0.z = fmaxf(acc0.z + bb.z, 0.f); o0.w = fmaxf(acc0.w + bb.w, 0.f);
  o1.x = fmaxf(acc1.x + bb.x, 0.f); o1.y = fmaxf(acc1.y + bb.y, 0.f);
  o1.z = fmaxf(acc1.z + bb.z, 0.f); o1.w = fmaxf(acc1.w + bb.w, 0.f);
  int r0 = row0 + rl * 2;
  *(float4*)&C[r0 * HID_C + cg * 4] = o0;
  *(float4*)&C[(r0 + 1) * HID_C + cg * 4] = o1;
  if (ssq_out) {
    float s0 = o0.x * o0.x + o0.y * o0.y + o0.z * o0.z + o0.w * o0.w;
    float s1 = o1.x * o1.x + o1.y * o1.y + o1.z * o1.z + o1.w * o1.w;
#pragma unroll
    for (int off = 16; off >= 1; off >>= 1) {
      s0 += __shfl_xor(s0, off, 64);
      s1 += __shfl_xor(s1, off, 64);
    }
    if (cg == 0) {
      ssq_out[r0] = s0;
      ssq_out[r0 + 1] = s1;
      invn_out[r0] = 1.0f / fmaxf(sqrtf(s0), 1e-12f);
      invn_out[r0 + 1] = 1.0f / fmaxf(sqrtf(s1), 1e-12f);
    }
  }
}

// ---------------- fused: blocks [0,nblk_gemm) do GEMM1; the rest build bitmaps + dup list ----------------
__global__ __launch_bounds__(256) void k_build_gemm(
    const float* __restrict__ X, const float* __restrict__ W, const float* __restrict__ b,
    float* __restrict__ C, int K, float* __restrict__ ssq_out, float* __restrict__ invn_out,
    int nblk_gemm,
    const int* __restrict__ src, const int* __restrict__ dst, int E,
    u64* __restrict__ bmT, u64* __restrict__ bmS, int wpr,
    u64* __restrict__ duplist, int* __restrict__ dupcnt, int dupcap) {
  __shared__ float Ws[64][HID_C + 4];
  __shared__ float Xs[16][64];
  if ((int)blockIdx.x < nblk_gemm) {
    gemm_body(blockIdx.x, threadIdx.x, X, W, b, C, K, ssq_out, invn_out, Ws, Xs);
    return;
  }
  int e = (blockIdx.x - nblk_gemm) * 256 + threadIdx.x;
  if (e < E) {
    int s = src[e], d = dst[e];
    u64 bit = 1ull << (s & 63);
    u64 old = atomicOr(&bmT[(size_t)d * wpr + (s >> 6)], bit);
    if (old & bit) {  // duplicate edge (multiplicity-1 extra copies recorded)
      int i = atomicAdd(dupcnt, 1);
      if (i < dupcap) duplist[i] = ((u64)(uint32_t)d << 32) | (uint32_t)s;
    }
    atomicOr(&bmS[(size_t)s * wpr + (d >> 6)], 1ull << (d & 63));
  }
}

// ---------------- standalone GEMM (second layer) ----------------
__global__ __launch_bounds__(256) void k_gemm_relu(
    const float* __restrict__ X, const float* __restrict__ W,
    const float* __restrict__ b, float* __restrict__ C, int K,
    float* __restrict__ ssq_out, float* __restrict__ invn_out) {
  __shared__ float Ws[64][HID_C + 4];
  __shared__ float Xs[16][64];
  gemm_body(blockIdx.x, threadIdx.x, X, W, b, C, K, ssq_out, invn_out, Ws, Xs);
}

// ---------------- AGNN propagation from transpose-bitmap, one wave per dst node ----------------
__global__ void k_agg(const float* __restrict__ hin, float* __restrict__ hout,
                      const u64* __restrict__ bmT, int wpr,
                      const u64* __restrict__ duplist, const int* __restrict__ dupcnt, int dupcap,
                      const float* __restrict__ invn, const float* __restrict__ ssq,
                      const float* __restrict__ beta_ptr,
                      float* __restrict__ ssq_out, float* __restrict__ invn_out,
                      int n) {
  __shared__ int s_src[4][SRC_CAP];
  int wv = threadIdx.x >> 6;
  int wid = (blockIdx.x * blockDim.x + threadIdx.x) >> 6;
  int lane = threadIdx.x & 63;
  if (wid >= n) return;

  // ---- enumerate src list from bitmap row into per-wave LDS (fixed deterministic order) ----
  const u64* row = bmT + (size_t)wid * wpr;
  u64 w0 = row[lane];
  u64 w1 = row[64 + lane];
  int c = __popcll(w0) + __popcll(w1);
  int incl = c;
#pragma unroll
  for (int off = 1; off < 64; off <<= 1) {
    int v = __shfl_up(incl, off, 64);
    if (lane >= off) incl += v;
  }
  int M = __shfl(incl, 63, 64);
  int pos = incl - c;
  u64 t = w0;
  while (t) {
    int bpos = __ffsll(t) - 1; t &= t - 1;
    if (pos < SRC_CAP) s_src[wv][pos] = (lane << 6) + bpos;
    pos++;
  }
  t = w1;
  while (t) {
    int bpos = __ffsll(t) - 1; t &= t - 1;
    if (pos < SRC_CAP) s_src[wv][pos] = ((64 + lane) << 6) + bpos;
    pos++;
  }
  if (M > SRC_CAP) M = SRC_CAP;

  // ---- append duplicate edges for this node (ascending s, multiplicity-exact, deterministic) ----
  int D = min(*dupcnt, dupcap);
  for (int base = 0; base < D; base += 64) {
    int m = min(64, D - base);
    bool match = false; int sE = 0x7fffffff;
    if (lane < m) {
      u64 ent = duplist[base + lane];
      if ((int)(ent >> 32) == wid) { match = true; sE = (int)(uint32_t)ent; }
    }
    while (__ballot(match)) {
      int sv = match ? sE : 0x7fffffff;
#pragma unroll
      for (int o = 32; o >= 1; o >>= 1) sv = min(sv, __shfl_xor(sv, o, 64));
      int cnt = (int)__popcll(__ballot(match && sE == sv));
      if (lane < cnt && M + lane < SRC_CAP) s_src[wv][M + lane] = sv;
      M = min(M + cnt, SRC_CAP);
      if (match && sE == sv) match = false;
    }
  }

  // ---- fused softmax + aggregate over [self-loop] + M srcs ----
  float beta = beta_ptr ? beta_ptr[0] : 1.0f;
  float2 hd = *(const float2*)&hin[wid * HID_C + lane * 2];
  float invd = invn[wid];
  float eloop = __expf(beta * (ssq[wid] * invd) * invd);  // self-loop; 0-row safe
  float ssum = eloop;
  float2 acc = make_float2(eloop * hd.x, eloop * hd.y);
  for (int cb = 0; cb < M; cb += 64) {
    int m = min(64, M - cb);
    int src_l = 0;
    float inv_l = 0.f;
    if (lane < m) {
      src_l = s_src[wv][cb + lane];
      inv_l = invn[src_l];
    }
    int p = 0;
    for (; p + 1 < m; p += 2) {
      int sa = __shfl(src_l, p, 64);
      int sb = __shfl(src_l, p + 1, 64);
      float ia = __shfl(inv_l, p, 64);
      float ib = __shfl(inv_l, p + 1, 64);
      float2 ha = *(const float2*)&hin[sa * HID_C + lane * 2];
      float2 hb = *(const float2*)&hin[sb * HID_C + lane * 2];
      float da = hd.x * ha.x + hd.y * ha.y;
      float db = hd.x * hb.x + hd.y * hb.y;
#pragma unroll
      for (int off = 32; off >= 1; off >>= 1) {
        da += __shfl_xor(da, off, 64);
        db += __shfl_xor(db, off, 64);
      }
      float ea = __expf(beta * da * invd * ia);
      float eb = __expf(beta * db * invd * ib);
      ssum += ea + eb;
      acc.x = fmaf(ea, ha.x, acc.x); acc.y = fmaf(ea, ha.y, acc.y);
      acc.x = fmaf(eb, hb.x, acc.x); acc.y = fmaf(eb, hb.y, acc.y);
    }
    if (p < m) {
      int sa = __shfl(src_l, p, 64);
      float ia = __shfl(inv_l, p, 64);
      float2 ha = *(const float2*)&hin[sa * HID_C + lane * 2];
      float da = hd.x * ha.x + hd.y * ha.y;
#pragma unroll
      for (int off = 32; off >= 1; off >>= 1) da += __shfl_xor(da, off, 64);
      float ea = __expf(beta * da * invd * ia);
      ssum += ea;
      acc.x = fmaf(ea, ha.x, acc.x); acc.y = fmaf(ea, ha.y, acc.y);
    }
  }
  float winv = 1.0f / (ssum + 1e-16f);
  acc.x *= winv; acc.y *= winv;
  *(float2*)&hout[wid * HID_C + lane * 2] = acc;
  if (ssq_out) {
    float s = acc.x * acc.x + acc.y * acc.y;
#pragma unroll
    for (int off = 32; off >= 1; off >>= 1) s += __shfl_xor(s, off, 64);
    if (lane == 0) {
      ssq_out[wid] = s;
      invn_out[wid] = 1.0f / fmaxf(sqrtf(s), 1e-12f);
    }
  }
}

// ---------------- out = adj @ h via src-major bitmap, one wave per output row ----------------
__global__ void k_mm_bits(const u64* __restrict__ bm, const float* __restrict__ h,
                          float* __restrict__ out, int n, int wpr) {
  int wid = (blockIdx.x * blockDim.x + threadIdx.x) >> 6;
  int lane = threadIdx.x & 63;
  if (wid >= n) return;
  const u64* row = bm + (size_t)wid * wpr;
  float2 acc = make_float2(0.f, 0.f);
  for (int base = 0; base < wpr; base += 64) {
    u64 w = row[base + lane];
    u64 mask = __ballot(w != 0);
    while (mask) {
      int l = __ffsll(mask) - 1;
      mask &= mask - 1;
      u64 wl = shfl_u64(w, l);
      int kbase = (base + l) << 6;
      while (wl) {
        int bit = __ffsll(wl) - 1;
        wl &= wl - 1;
        int k = kbase + bit;
        float2 hv = *(const float2*)&h[k * HID_C + lane * 2];
        acc.x += hv.x;
        acc.y += hv.y;
      }
    }
  }
  *(float2*)&out[wid * HID_C + lane * 2] = acc;
}

extern "C" void kernel_launch(void* const* d_in, const int* in_sizes, int n_in,
                              void* d_out, int out_size, void* d_ws, size_t ws_size,
                              hipStream_t stream) {
  const float* x     = (const float*)d_in[0];
  const int*   eio   = (const int*)d_in[2];
  const float* W1    = (const float*)d_in[3];
  const float* b1    = (const float*)d_in[4];
  const float* W2    = (const float*)d_in[5];
  const float* b2    = (const float*)d_in[6];
  const float* beta2 = (const float*)d_in[7];
  float* out = (float*)d_out;

  const int N = in_sizes[0] / IN_C;   // 8192
  const int E = in_sizes[2] / 2;      // 262144
  const int WPR = N / 64;             // bitmap words per row (128)
  const int* esrc = eio;
  const int* edst = eio + E;
  const int DUPCAP = E;

  // ---- workspace layout (256B aligned slots) ----
  size_t off = 0;
  auto take = [&](size_t bytes) -> size_t {
    size_t o = off;
    off = (off + bytes + 255) & ~(size_t)255;
    return o;
  };
  size_t o_bufA   = take((size_t)N * HID_C * 4);
  size_t o_bufB   = take((size_t)N * HID_C * 4);
  size_t o_invnA  = take((size_t)N * 4);
  size_t o_ssqA   = take((size_t)N * 4);
  size_t o_invnB  = take((size_t)N * 4);
  size_t o_ssqB   = take((size_t)N * 4);
  size_t o_bmT    = take((size_t)N * WPR * 8);   // zeroed region starts here
  size_t o_bmS    = take((size_t)N * WPR * 8);
  size_t o_dupcnt = take(256);
  size_t need_zero_end = o_dupcnt + 256;
  size_t o_duplist = take((size_t)DUPCAP * 8);
  size_t need_full = off;

  unsigned char* base = (unsigned char*)d_ws;
  if (ws_size < need_full) {
    void* p = nullptr;
    hipGetSymbolAddress(&p, HIP_SYMBOL(g_fallback));
    base = (unsigned char*)p;
  }

  float* bufA    = (float*)(base + o_bufA);
  float* bufB    = (float*)(base + o_bufB);
  float* invnA   = (float*)(base + o_invnA);
  float* ssqA    = (float*)(base + o_ssqA);
  float* invnB   = (float*)(base + o_invnB);
  float* ssqB    = (float*)(base + o_ssqB);
  u64*   bmT     = (u64*)(base + o_bmT);
  u64*   bmS     = (u64*)(base + o_bmS);
  int*   dupcnt  = (int*)(base + o_dupcnt);
  u64*   duplist = (u64*)(base + o_duplist);

  dim3 blk(256);

  // 1. zero bitmaps + dup counter with our own grid-stride kernel.
  //    (rocclr fillBufferAligned ran this 16.8 MB fill at ~108 GB/s = ~155 us,
  //     dominating the whole graph — measured R4/R5 counters.)
  {
    size_t zbytes = need_zero_end - o_bmT;
    int n16 = (int)(zbytes / 16);
    k_zero128<<<dim3(4096), blk, 0, stream>>>((uint4*)(base + o_bmT), n16);
  }

  // 2. fused: GEMM1 (h1 = relu(x@W1^T+b1) + norms) || bitmap/dup build
  {
    int nblk_gemm = N / 16;                  // 512
    int nblk_build = (E + 255) / 256;        // 1024
    k_build_gemm<<<dim3(nblk_gemm + nblk_build), blk, 0, stream>>>(
        x, W1, b1, bufA, IN_C, ssqA, invnA, nblk_gemm,
        esrc, edst, E, bmT, bmS, WPR, duplist, dupcnt, DUPCAP);
  }

  // 3. prop1 (beta = 1.0), + row norms of output
  k_agg<<<dim3(N / 4), blk, 0, stream>>>(bufA, bufB, bmT, WPR, duplist, dupcnt, DUPCAP,
                                         invnA, ssqA, nullptr, ssqB, invnB, N);

  // 4. prop2 (beta = beta2[0])
  k_agg<<<dim3(N / 4), blk, 0, stream>>>(bufB, bufA, bmT, WPR, duplist, dupcnt, DUPCAP,
                                         invnB, ssqB, beta2, nullptr, nullptr, N);

  // 5. h3 = relu(h @ W2^T + b2)
  k_gemm_relu<<<dim3(N / 16), blk, 0, stream>>>(bufA, W2, b2, bufB, HID_C, nullptr, nullptr);

  // 6. out = adj @ h3
  k_mm_bits<<<dim3(N / 4), blk, 0, stream>>>(bmS, bufB, out, N, WPR);
}